// Round 5
// baseline (277.297 us; speedup 1.0000x reference)
//
#include <hip/hip_runtime.h>
#include <stdint.h>

typedef __attribute__((ext_vector_type(8))) short short8;
typedef __attribute__((ext_vector_type(4))) float floatx4;
typedef __attribute__((ext_vector_type(16))) float floatx16;
typedef __attribute__((ext_vector_type(2))) unsigned int uintx2;
typedef unsigned short u16;
typedef unsigned int u32;

#define EDIM 128
#define FDIM 512
#define BM 64
#define QSTR (EDIM + 8)   // 136 bf16 = 272 B row stride (16B aligned)
#define HSTR (128 + 8)    // 136 bf16
#define NTILE 2048
#define GRID 768          // persistent; 3 blocks/CU resident, 2-3 tiles each

// round-to-nearest-even float -> bf16 (prep path)
__device__ __forceinline__ u32 f2bf_rne(float f) {
    u32 u = __builtin_bit_cast(u32, f);
    return (u + 0x7fffu + ((u >> 16) & 1u)) >> 16;
}
__device__ __forceinline__ u32 pk2bf(float lo, float hi) {
    return f2bf_rne(lo) | (f2bf_rne(hi) << 16);
}
// HW packed f32x2 -> bf16x2, RNE (main path)
__device__ __forceinline__ u32 cvtpk(float lo, float hi) {
    u32 r;
    asm("v_cvt_pk_bf16_f32 %0, %1, %2" : "=v"(r) : "v"(lo), "v"(hi));
    return r;
}

// Pre-swizzle W1/W2 to bf16 in MFMA A-fragment lane order:
//   W1s group g  = ft*512 + k*64 + lane   (16B per group)
//        holds W1[ft*32 + (lane&31)][k*16 + (lane>>5)*8 + j], j=0..7
//   W2s group g2 = (et*4+c)*512 + k*64 + lane
//        holds W2[et*32 + (lane&31)][c*128 + k*16 + (lane>>5)*8 + j]
// Also: cth[e] = cos(theta[e]) as f32 at wb + 2*FDIM*EDIM (u16 offset).
__global__ __launch_bounds__(256) void ffq_prep(const float* __restrict__ W1,
                                                const float* __restrict__ W2,
                                                const float* __restrict__ theta,
                                                u16* __restrict__ wb) {
    int g = blockIdx.x * 256 + threadIdx.x;   // 0..16383
    int lane = g & 63;
    int kk = (g >> 6) & 7;
    int idx = (g >> 9) & 15;
    int l31 = lane & 31, h5 = lane >> 5;
    if (g < 128) {
        float* cth = reinterpret_cast<float*>(wb + 2 * FDIM * EDIM);
        cth[g] = cosf(theta[g]);
    }
    const float* src;
    if (g < 8192) {
        src = W1 + (idx * 32 + l31) * EDIM + kk * 16 + h5 * 8;
    } else {
        int gg = idx >> 2, c = idx & 3;
        src = W2 + (gg * 32 + l31) * FDIM + c * 128 + kk * 16 + h5 * 8;
    }
    float4 v0 = *reinterpret_cast<const float4*>(src);
    float4 v1 = *reinterpret_cast<const float4*>(src + 4);
    uint4 p;
    p.x = pk2bf(v0.x, v0.y);
    p.y = pk2bf(v0.z, v0.w);
    p.z = pk2bf(v1.x, v1.y);
    p.w = pk2bf(v1.z, v1.w);
    reinterpret_cast<uint4*>(wb)[g] = p;
}

// Fused q = cos(x)*cos(theta); h = relu(q@W1^T); out = h@W2^T.
// Round-0 structure exactly (64 rows/tile, 8 waves, q staged in LDS, h via
// LDS double buffer, 1 barrier per f-chunk, q B-frags read from LDS per
// MFMA). Persistent blocks grid-stride over tiles with the NEXT tile's x
// prefetched into 16 VGPRs right after the staging barrier (T14) — the only
// delta vs round 0. No qf hoist (that was round 3's spill).
__global__ __launch_bounds__(512, 4) void ffq_main(const float* __restrict__ x,
                                                   const u16* __restrict__ wb,
                                                   float* __restrict__ out) {
    __shared__ u16 qs[BM * QSTR];       // 17408 B
    __shared__ u16 hs[2][BM * HSTR];    // 34816 B (total 52224 B -> 3 blocks/CU)

    const int t = threadIdx.x;
    const int lane = t & 63;
    const int wv = t >> 6;        // wave id 0..7
    const int l31 = lane & 31;
    const int h5 = lane >> 5;     // half-wave 0/1
    const int mg = wv & 1;        // m-group: rows mg*32..mg*32+31
    const int gg = wv >> 1;       // f-group (GEMM1) / e-group (GEMM2): 0..3

    const u16* W1s = wb;
    const u16* W2s = wb + FDIM * EDIM;
    const float* cth = reinterpret_cast<const float*>(wb + 2 * FDIM * EDIM);

    const int et = (t & 31) * 4;  // e offset; same each r since 512 % 32 == 0
    const float c0 = cth[et + 0];
    const float c1 = cth[et + 1];
    const float c2 = cth[et + 2];
    const float c3 = cth[et + 3];

    const u16* w1l = W1s + lane * 8;
    const u16* w2l = W2s + lane * 8;
    const u16* qp  = &qs[(mg * 32 + l31) * QSTR + h5 * 8];  // B-frag base (q)
    const u16* hp0 = &hs[0][(mg * 32 + l31) * HSTR + h5 * 8];
    const u16* hp1 = &hs[1][(mg * 32 + l31) * HSTR + h5 * 8];

    // ---- preload first tile's x into registers ----
    float4 xv[4];
    {
        const float4* xin = reinterpret_cast<const float4*>(x) +
                            (size_t)blockIdx.x * (BM * EDIM / 4);
        #pragma unroll
        for (int r = 0; r < 4; ++r) xv[r] = xin[t + 512 * r];
    }

    for (int tile = blockIdx.x; tile < NTILE; tile += GRID) {
        // ---- stage q = cos(x)*cos(theta) into LDS (bf16) from regs ----
        #pragma unroll
        for (int r = 0; r < 4; ++r) {
            int m = (t + 512 * r) >> 5;   // row 0..63
            float4 v = xv[r];
            uintx2 p;
            p.x = pk2bf(__cosf(v.x) * c0, __cosf(v.y) * c1);
            p.y = pk2bf(__cosf(v.z) * c2, __cosf(v.w) * c3);
            *reinterpret_cast<uintx2*>(&qs[m * QSTR + et]) = p;
        }
        __syncthreads();

        // ---- prefetch next tile's x; in flight across this tile's MFMAs ----
        if (tile + GRID < NTILE) {
            const float4* xin = reinterpret_cast<const float4*>(x) +
                                (size_t)(tile + GRID) * (BM * EDIM / 4);
            #pragma unroll
            for (int r = 0; r < 4; ++r) xv[r] = xin[t + 512 * r];
        }

        floatx16 acc2 = {0.f,0.f,0.f,0.f,0.f,0.f,0.f,0.f,
                         0.f,0.f,0.f,0.f,0.f,0.f,0.f,0.f};  // out^T 32x32 tile

        #pragma unroll
        for (int c = 0; c < 4; ++c) {
            // ---- GEMM1: h^T 32x32 tile = W1_tile x q^T, K = 128 ----
            floatx16 acc1 = {0.f,0.f,0.f,0.f,0.f,0.f,0.f,0.f,
                             0.f,0.f,0.f,0.f,0.f,0.f,0.f,0.f};
            const u16* w1p = w1l + (size_t)(c * 4 + gg) * 4096;
            #pragma unroll
            for (int k = 0; k < 8; ++k) {
                short8 a = *reinterpret_cast<const short8*>(w1p + k * 512);
                short8 b = *reinterpret_cast<const short8*>(qp + k * 16);
                acc1 = __builtin_amdgcn_mfma_f32_32x32x16_bf16(a, b, acc1, 0, 0, 0);
            }

            // relu + bf16 -> h buffer. D: col m=l31, row f=(reg&3)+8*(reg>>2)+4*h5
            u16* hb = hs[c & 1];
            const int hrow = (mg * 32 + l31) * HSTR;
            #pragma unroll
            for (int rq = 0; rq < 4; ++rq) {
                const int fl = gg * 32 + rq * 8 + h5 * 4;
                uintx2 p;
                p.x = cvtpk(fmaxf(acc1[rq * 4 + 0], 0.f), fmaxf(acc1[rq * 4 + 1], 0.f));
                p.y = cvtpk(fmaxf(acc1[rq * 4 + 2], 0.f), fmaxf(acc1[rq * 4 + 3], 0.f));
                *reinterpret_cast<uintx2*>(&hb[hrow + fl]) = p;
            }
            __syncthreads();   // the only barrier this chunk

            // ---- GEMM2: out^T 32x32 tile += W2_tile x h^T, chunk K = 128 ----
            const u16* w2p = w2l + (size_t)(gg * 4 + c) * 4096;
            const u16* hpc = (c & 1) ? hp1 : hp0;
            #pragma unroll
            for (int k = 0; k < 8; ++k) {
                short8 a = *reinterpret_cast<const short8*>(w2p + k * 512);
                short8 b = *reinterpret_cast<const short8*>(hpc + k * 16);
                acc2 = __builtin_amdgcn_mfma_f32_32x32x16_bf16(a, b, acc2, 0, 0, 0);
            }
        }

        // ---- epilogue: D col m=l31, row e=gg*32+(reg&3)+8*(reg>>2)+4*h5 ----
        float* op = out + (size_t)tile * BM * EDIM +
                    (mg * 32 + l31) * EDIM + gg * 32 + h5 * 4;
        #pragma unroll
        for (int rq = 0; rq < 4; ++rq) {
            floatx4 v;
            v[0] = acc2[rq * 4 + 0];
            v[1] = acc2[rq * 4 + 1];
            v[2] = acc2[rq * 4 + 2];
            v[3] = acc2[rq * 4 + 3];
            *reinterpret_cast<floatx4*>(op + rq * 8) = v;
        }
    }
}

extern "C" void kernel_launch(void* const* d_in, const int* in_sizes, int n_in,
                              void* d_out, int out_size, void* d_ws, size_t ws_size,
                              hipStream_t stream) {
    const float* x     = (const float*)d_in[0];  // [32,4096,128]
    const float* theta = (const float*)d_in[1];  // [128]
    const float* W1    = (const float*)d_in[2];  // [512,128]
    const float* W2    = (const float*)d_in[3];  // [128,512]
    u16* wb    = (u16*)d_ws;                     // 256 KB bf16 weights + cos(theta) table
    float* out = (float*)d_out;                  // [32,4096,128]

    ffq_prep<<<64, 256, 0, stream>>>(W1, W2, theta, wb);
    ffq_main<<<GRID, 512, 0, stream>>>(x, wb, out);
}

// Round 6
// 145.007 us; speedup vs baseline: 1.9123x; 1.9123x over previous
//
#include <hip/hip_runtime.h>
#include <stdint.h>

typedef __attribute__((ext_vector_type(8))) short short8;
typedef __attribute__((ext_vector_type(4))) float floatx4;
typedef __attribute__((ext_vector_type(16))) float floatx16;
typedef __attribute__((ext_vector_type(2))) unsigned int uintx2;
typedef unsigned short u16;
typedef unsigned int u32;

#define EDIM 128
#define FDIM 512
#define BM 128            // rows per block (two 32-row tiles per wave)
#define QSTR (EDIM + 8)   // 136 bf16 = 272 B row stride (16B aligned)
#define HSTR (128 + 8)    // 136 bf16

// round-to-nearest-even float -> bf16 (prep path)
__device__ __forceinline__ u32 f2bf_rne(float f) {
    u32 u = __builtin_bit_cast(u32, f);
    return (u + 0x7fffu + ((u >> 16) & 1u)) >> 16;
}
__device__ __forceinline__ u32 pk2bf(float lo, float hi) {
    return f2bf_rne(lo) | (f2bf_rne(hi) << 16);
}
// HW packed f32x2 -> bf16x2, RNE (main path)
__device__ __forceinline__ u32 cvtpk(float lo, float hi) {
    u32 r;
    asm("v_cvt_pk_bf16_f32 %0, %1, %2" : "=v"(r) : "v"(lo), "v"(hi));
    return r;
}

// Pre-swizzle W1/W2 to bf16 in MFMA A-fragment lane order:
//   W1s group g  = ft*512 + k*64 + lane   (16B per group)
//        holds W1[ft*32 + (lane&31)][k*16 + (lane>>5)*8 + j], j=0..7
//   W2s group g2 = (et*4+c)*512 + k*64 + lane
//        holds W2[et*32 + (lane&31)][c*128 + k*16 + (lane>>5)*8 + j]
// Also: cth[e] = cos(theta[e]) as f32 at wb + 2*FDIM*EDIM (u16 offset).
__global__ __launch_bounds__(256) void ffq_prep(const float* __restrict__ W1,
                                                const float* __restrict__ W2,
                                                const float* __restrict__ theta,
                                                u16* __restrict__ wb) {
    int g = blockIdx.x * 256 + threadIdx.x;   // 0..16383
    int lane = g & 63;
    int kk = (g >> 6) & 7;
    int idx = (g >> 9) & 15;
    int l31 = lane & 31, h5 = lane >> 5;
    if (g < 128) {
        float* cth = reinterpret_cast<float*>(wb + 2 * FDIM * EDIM);
        cth[g] = cosf(theta[g]);
    }
    const float* src;
    if (g < 8192) {
        src = W1 + (idx * 32 + l31) * EDIM + kk * 16 + h5 * 8;
    } else {
        int gg = idx >> 2, c = idx & 3;
        src = W2 + (gg * 32 + l31) * FDIM + c * 128 + kk * 16 + h5 * 8;
    }
    float4 v0 = *reinterpret_cast<const float4*>(src);
    float4 v1 = *reinterpret_cast<const float4*>(src + 4);
    uint4 p;
    p.x = pk2bf(v0.x, v0.y);
    p.y = pk2bf(v0.z, v0.w);
    p.z = pk2bf(v1.x, v1.y);
    p.w = pk2bf(v1.z, v1.w);
    reinterpret_cast<uint4*>(wb)[g] = p;
}

// Fused q = cos(x)*cos(theta); h = relu(q@W1^T); out = h@W2^T.
// 128 rows/block, 8 waves = (gg 0..3) x (mp 0..1). Each wave runs TWO
// independent accumulator chains (m-tiles mp*64+0 and mp*64+32), sharing
// every A-fragment load -> 2x MFMA ILP per wave at R0's occupancy.
// h through a single LDS buffer (ready-barrier + WAR-barrier per chunk,
// same 16-MFMA-per-interval rhythm as R0's double buffer).
__global__ __launch_bounds__(512, 4) void ffq_main(const float* __restrict__ x,
                                                   const u16* __restrict__ wb,
                                                   float* __restrict__ out) {
    __shared__ u16 qs[BM * QSTR];   // 34816 B
    __shared__ u16 hs[BM * HSTR];   // 34816 B (total 69632 -> 2 blocks/CU)

    const int t = threadIdx.x;
    const int lane = t & 63;
    const int wv = t >> 6;        // wave id 0..7
    const int l31 = lane & 31;
    const int h5 = lane >> 5;     // half-wave 0/1
    const int mp = wv & 1;        // m-pair: rows mp*64 .. mp*64+63
    const int gg = wv >> 1;       // f-group (GEMM1) / e-group (GEMM2): 0..3

    const u16* W1s = wb;
    const u16* W2s = wb + FDIM * EDIM;
    const float* cth = reinterpret_cast<const float*>(wb + 2 * FDIM * EDIM);

    // ---- stage q = cos(x)*cos(theta) into LDS (bf16), coalesced ----
    {
        const float4* xin = reinterpret_cast<const float4*>(x) +
                            (size_t)blockIdx.x * (BM * EDIM / 4);
        const int et = (t & 31) * 4;  // e offset; same each r since 512 % 32 == 0
        float c0 = cth[et + 0];
        float c1 = cth[et + 1];
        float c2 = cth[et + 2];
        float c3 = cth[et + 3];
        #pragma unroll
        for (int r = 0; r < 8; ++r) {
            int i = t + 512 * r;   // float4 index within tile
            int m = i >> 5;        // row 0..127
            float4 v = xin[i];
            uintx2 p;
            p.x = pk2bf(__cosf(v.x) * c0, __cosf(v.y) * c1);
            p.y = pk2bf(__cosf(v.z) * c2, __cosf(v.w) * c3);
            *reinterpret_cast<uintx2*>(&qs[m * QSTR + et]) = p;
        }
    }
    __syncthreads();

    const floatx16 zero = {0.f,0.f,0.f,0.f,0.f,0.f,0.f,0.f,
                           0.f,0.f,0.f,0.f,0.f,0.f,0.f,0.f};
    floatx16 acc2[2] = {zero, zero};   // out^T tiles, rows mp*64+{0,32}

    const u16* w1l = W1s + lane * 8;
    const u16* w2l = W2s + lane * 8;
    // q/h B-frag bases for the two m-tiles
    const u16* qp0 = &qs[(mp * 64 + l31) * QSTR + h5 * 8];
    const u16* qp1 = qp0 + 32 * QSTR;
    const u16* hp0 = &hs[(mp * 64 + l31) * HSTR + h5 * 8];
    const u16* hp1 = hp0 + 32 * HSTR;

    #pragma unroll
    for (int c = 0; c < 4; ++c) {
        // ---- GEMM1: two 32x32 h^T tiles, shared A-frags, K = 128 ----
        floatx16 a1[2] = {zero, zero};
        const u16* w1p = w1l + (size_t)(c * 4 + gg) * 4096;
        #pragma unroll
        for (int k = 0; k < 8; ++k) {
            short8 a  = *reinterpret_cast<const short8*>(w1p + k * 512);
            short8 b0 = *reinterpret_cast<const short8*>(qp0 + k * 16);
            short8 b1 = *reinterpret_cast<const short8*>(qp1 + k * 16);
            a1[0] = __builtin_amdgcn_mfma_f32_32x32x16_bf16(a, b0, a1[0], 0, 0, 0);
            a1[1] = __builtin_amdgcn_mfma_f32_32x32x16_bf16(a, b1, a1[1], 0, 0, 0);
        }

        // relu + bf16 -> h. D: col m=l31, row f=(reg&3)+8*(reg>>2)+4*h5
        #pragma unroll
        for (int s = 0; s < 2; ++s) {
            const int hrow = (mp * 64 + s * 32 + l31) * HSTR;
            #pragma unroll
            for (int rq = 0; rq < 4; ++rq) {
                const int fl = gg * 32 + rq * 8 + h5 * 4;
                uintx2 p;
                p.x = cvtpk(fmaxf(a1[s][rq * 4 + 0], 0.f), fmaxf(a1[s][rq * 4 + 1], 0.f));
                p.y = cvtpk(fmaxf(a1[s][rq * 4 + 2], 0.f), fmaxf(a1[s][rq * 4 + 3], 0.f));
                *reinterpret_cast<uintx2*>(&hs[hrow + fl]) = p;
            }
        }
        __syncthreads();   // h ready

        // ---- GEMM2: two out^T tiles += W2_tile x h^T, chunk K = 128 ----
        const u16* w2p = w2l + (size_t)(gg * 4 + c) * 4096;
        #pragma unroll
        for (int k = 0; k < 8; ++k) {
            short8 a  = *reinterpret_cast<const short8*>(w2p + k * 512);
            short8 b0 = *reinterpret_cast<const short8*>(hp0 + k * 16);
            short8 b1 = *reinterpret_cast<const short8*>(hp1 + k * 16);
            acc2[0] = __builtin_amdgcn_mfma_f32_32x32x16_bf16(a, b0, acc2[0], 0, 0, 0);
            acc2[1] = __builtin_amdgcn_mfma_f32_32x32x16_bf16(a, b1, acc2[1], 0, 0, 0);
        }
        __syncthreads();   // WAR: hs consumed, next chunk may overwrite
    }

    // ---- epilogue: D col m=l31, row e=gg*32+(reg&3)+8*(reg>>2)+4*h5 ----
    #pragma unroll
    for (int s = 0; s < 2; ++s) {
        float* op = out + (size_t)blockIdx.x * BM * EDIM +
                    (mp * 64 + s * 32 + l31) * EDIM + gg * 32 + h5 * 4;
        #pragma unroll
        for (int rq = 0; rq < 4; ++rq) {
            floatx4 v;
            v[0] = acc2[s][rq * 4 + 0];
            v[1] = acc2[s][rq * 4 + 1];
            v[2] = acc2[s][rq * 4 + 2];
            v[3] = acc2[s][rq * 4 + 3];
            *reinterpret_cast<floatx4*>(op + rq * 8) = v;
        }
    }
}

extern "C" void kernel_launch(void* const* d_in, const int* in_sizes, int n_in,
                              void* d_out, int out_size, void* d_ws, size_t ws_size,
                              hipStream_t stream) {
    const float* x     = (const float*)d_in[0];  // [32,4096,128]
    const float* theta = (const float*)d_in[1];  // [128]
    const float* W1    = (const float*)d_in[2];  // [512,128]
    const float* W2    = (const float*)d_in[3];  // [128,512]
    u16* wb    = (u16*)d_ws;                     // 256 KB bf16 weights + cos(theta) table
    float* out = (float*)d_out;                  // [32,4096,128]

    ffq_prep<<<64, 256, 0, stream>>>(W1, W2, theta, wb);
    ffq_main<<<1024, 512, 0, stream>>>(x, wb, out);
}